// Round 16
// baseline (168.325 us; speedup 1.0000x reference)
//
#include <hip/hip_runtime.h>
#include <hip/hip_bf16.h>

// GAT MultiHeads, MI355X. N=4096, F_IN=256, H=8, D=16, HD=128.
// All inputs/outputs f32; attention inner loop packed f16 with f16 masks.
//
// Math identities (vs reference):
//  - logits[h,i,j] = f1[h,j] + f2[h,i]  (rank-1, never materialized)
//  - exp(lrelu(x)) = max(e^x, e^{0.3x})  (exp monotone, lrelu = max(x,0.3x))
//    => q = max(E1[j]*A[i], E3[j]*B[i]); E1=e^f1, E3=e^{0.3f1}, A=e^f2, B=e^{0.3f2}
//  - no max-subtraction: logits bounded (|x| < ~5), softmax ratio invariant
//  - g in {0,1} => exact in f16; mask applied as one packed-f16 multiply
//  - denominators = P @ ones via MFMA (idle pipe), lane gets its row sum
//  - fully-masked rows: denom clamp 1e-30 => output row 0 (matches densify)
//
// Pipeline: k_prep (cvt weights/X) / k_cvt (masks f32 -> f16, the full-BW
// 268MB streaming floor; each mask element is consumed by exactly ONE k_attn
// block so no reuse exists -- f16 is the zero-expansion-cost representation) /
// k_score (score GEMM + f16 exp tables) / k_attn (j-split x4: no LDS, no
// barriers, no scalar loads, ~26 VALU/iter) / k_reduce (sum + output GEMM).

#define NN 4096
#define LOG2E 1.44269504088896340736f
#define NS 4          // j-split chunks
#define CHUNK 1024    // NN/NS

typedef short bf16x8 __attribute__((ext_vector_type(8)));
typedef float f32x4  __attribute__((ext_vector_type(4)));
typedef _Float16 h16x8 __attribute__((ext_vector_type(8)));
typedef __fp16  fp16x2 __attribute__((ext_vector_type(2)));

__device__ __forceinline__ unsigned short f2bf_rn(float f) {
  union { float f; unsigned int i; } v; v.f = f;
  unsigned int r = v.i + 0x7FFFu + ((v.i >> 16) & 1u);  // RTNE
  return (unsigned short)(r >> 16);
}
// two f32 -> packed 2x f16 (RTZ) as u32
__device__ __forceinline__ unsigned int pk2(float lo, float hi) {
  fp16x2 h = __builtin_amdgcn_cvt_pkrtz(lo, hi);
  union { fp16x2 h; unsigned int u; } v; v.h = h; return v.u;
}

// ---- K0: one-time conversions. grid 512x256 ----
__global__ __launch_bounds__(256) void k_prep(
    const float* __restrict__ X, const float* __restrict__ Ww,
    const float* __restrict__ Wcat, const float* __restrict__ proj,
    const float* __restrict__ Wcb, const float* __restrict__ bias,
    const float* __restrict__ prb,
    unsigned short* __restrict__ Xb, unsigned short* __restrict__ WwT,
    unsigned short* __restrict__ WpT, float* __restrict__ bsum)
{
  const int tid = blockIdx.x * 256 + threadIdx.x;  // 0..131071
  {  // X[4096][256] f32 -> bf16 (RTNE), 8 elements/thread
    const float4 a = *(const float4*)(X + (size_t)tid * 8);
    const float4 b = *(const float4*)(X + (size_t)tid * 8 + 4);
    uint4 o;
    o.x = (unsigned)f2bf_rn(a.x) | ((unsigned)f2bf_rn(a.y) << 16);
    o.y = (unsigned)f2bf_rn(a.z) | ((unsigned)f2bf_rn(a.w) << 16);
    o.z = (unsigned)f2bf_rn(b.x) | ((unsigned)f2bf_rn(b.y) << 16);
    o.w = (unsigned)f2bf_rn(b.z) | ((unsigned)f2bf_rn(b.w) << 16);
    *(uint4*)(Xb + (size_t)tid * 8) = o;
  }
  if (tid < 32768) {  // WwT[c][k] = Ww[k][c], bf16
    int c = tid & 127, k = tid >> 7;
    WwT[c * 256 + k] = f2bf_rn(Ww[k * 128 + c]);
  }
  if (tid < 65536) {  // WpT[c][k]: k<256 -> Wcat[k][c], else proj[k-256][c]
    int c = tid & 127, k = tid >> 7;
    float v = (k < 256) ? Wcat[k * 128 + c] : proj[(k - 256) * 128 + c];
    WpT[c * 512 + k] = f2bf_rn(v);
  }
  if (tid < 128) bsum[tid] = Wcb[tid] + bias[tid] + prb[tid];
}

// ---- K0b: masks f32 -> f16, pure streaming. grid 16384 x 256 ----
// 8 elements/thread, coalesced read 32B / write 16B. Row-major layout kept.
__global__ __launch_bounds__(256) void k_cvt(
    const float* __restrict__ Dg, const float* __restrict__ Sg,
    unsigned short* __restrict__ mD, unsigned short* __restrict__ mS)
{
  const size_t tid = (size_t)blockIdx.x * 256 + threadIdx.x;  // 0..4194303
  const int g = (int)(tid >> 21);            // 2,097,152 threads per graph
  const float* src = g ? Sg : Dg;
  unsigned short* dst = g ? mS : mD;
  const size_t off = (tid & 0x1FFFFFull) * 8;
  const float4 a = *(const float4*)(src + off);
  const float4 b = *(const float4*)(src + off + 4);
  uint4 o;
  o.x = pk2(a.x, a.y); o.y = pk2(a.z, a.w);
  o.z = pk2(b.x, b.y); o.w = pk2(b.z, b.w);
  *(uint4*)(dst + off) = o;
}

// ---- K1: score GEMM + f2 + f16 exp tables. grid 256 x 512 ----
__global__ __launch_bounds__(512) void k_score(
    const unsigned short* __restrict__ Xb, const unsigned short* __restrict__ WwT,
    const float* __restrict__ Wb, const float* __restrict__ wu,
    const float* __restrict__ wv,
    unsigned short* __restrict__ scT, float* __restrict__ f2,
    unsigned short* __restrict__ E1p, unsigned short* __restrict__ E3p)
{
  const int n0 = blockIdx.x * 16;
  const int h = threadIdx.x >> 6, lane = threadIdx.x & 63;
  const int mr = lane & 15, grp = lane >> 4;
  const unsigned short* ap  = Xb  + (size_t)(n0 + mr) * 256;
  const unsigned short* bpp = WwT + (size_t)(h * 16 + mr) * 256;
  f32x4 acc = {0.f, 0.f, 0.f, 0.f};
  #pragma unroll
  for (int ks = 0; ks < 8; ++ks) {
    bf16x8 a = *(const bf16x8*)(ap  + ks * 32 + grp * 8);
    bf16x8 b = *(const bf16x8*)(bpp + ks * 32 + grp * 8);
    acc = __builtin_amdgcn_mfma_f32_16x16x32_bf16(a, b, acc, 0, 0, 0);
  }
  const float wb = Wb[h * 16 + mr];
  float sc[4];
  #pragma unroll
  for (int r = 0; r < 4; ++r) sc[r] = acc[r] + wb;  // score[n0+grp*4+r][h*16+mr]

  {  // scT[h*16+mr][n0+grp*4 .. +3] f16
    uint2 st;
    st.x = pk2(sc[0], sc[1]);
    st.y = pk2(sc[2], sc[3]);
    *(uint2*)(scT + (size_t)(h * 16 + mr) * NN + n0 + grp * 4) = st;
  }

  const float uw = wu[h * 16 + mr], vw = wv[h * 16 + mr];
  float t1[4], t2[4];
  #pragma unroll
  for (int r = 0; r < 4; ++r) { t1[r] = sc[r] * uw; t2[r] = sc[r] * vw; }
  #pragma unroll
  for (int m = 1; m < 16; m <<= 1) {
    #pragma unroll
    for (int r = 0; r < 4; ++r) {
      t1[r] += __shfl_xor(t1[r], m, 64);
      t2[r] += __shfl_xor(t2[r], m, 64);
    }
  }
  if (mr == 0) {
    *(float4*)(f2 + h * NN + n0 + grp * 4) = make_float4(t2[0], t2[1], t2[2], t2[3]);
    float e1[4], e3[4];
    #pragma unroll
    for (int r = 0; r < 4; ++r) {
      e1[r] = __builtin_amdgcn_exp2f(t1[r] * LOG2E);
      e3[r] = __builtin_amdgcn_exp2f(0.3f * t1[r] * LOG2E);
    }
    uint2 p1, p3;
    p1.x = pk2(e1[0], e1[1]);
    p1.y = pk2(e1[2], e1[3]);
    p3.x = pk2(e3[0], e3[1]);
    p3.y = pk2(e3[2], e3[3]);
    *(uint2*)(E1p + h * NN + n0 + grp * 4) = p1;
    *(uint2*)(E3p + h * NN + n0 + grp * 4) = p3;
  }
}

// ---- K2: dual-graph masked softmax attention, j-split x NS ----
// grid = NS*256 (bx = chunk*256 + tile), 512 thr (8 waves = 8 heads).
// No LDS, no barriers, no scalar loads, no inline asm. Per iter: 5
// independent 16B loads + ~26 VALU + 4 MFMA; 8 waves/SIMD hide latency.
__global__ __launch_bounds__(512, 8) void k_attn(
    const unsigned short* __restrict__ mD, const unsigned short* __restrict__ mS,
    const unsigned short* __restrict__ scT, const unsigned short* __restrict__ E1p,
    const unsigned short* __restrict__ E3p, const float* __restrict__ f2,
    float* __restrict__ pn, float* __restrict__ pd)
{
  const int bx = blockIdx.x;
  const int c = bx >> 8, t = bx & 255;
  const int i0 = t << 4, j0 = c * CHUNK;
  const int h = threadIdx.x >> 6, lane = threadIdx.x & 63;
  const int mr = lane & 15, grp = lane >> 4;

  const float f2v = f2[h * NN + i0 + mr];
  const _Float16 afh = (_Float16)__builtin_amdgcn_exp2f(f2v * LOG2E);
  const _Float16 bfh = (_Float16)__builtin_amdgcn_exp2f(0.3f * f2v * LOG2E);
  const h16x8 af8 = {afh, afh, afh, afh, afh, afh, afh, afh};
  const h16x8 bf8 = {bfh, bfh, bfh, bfh, bfh, bfh, bfh, bfh};
  const _Float16 one = (_Float16)1.f;
  const h16x8 ones = {one, one, one, one, one, one, one, one};

  const _Float16* e1p_ = (const _Float16*)E1p + h * NN + j0 + grp * 8;
  const _Float16* e3p_ = (const _Float16*)E3p + h * NN + j0 + grp * 8;
  const _Float16* scp_ = (const _Float16*)scT + (size_t)(h * 16 + mr) * NN + j0 + grp * 8;
  const _Float16* mDp  = (const _Float16*)mD + (size_t)(i0 + mr) * NN + j0 + grp * 8;
  const _Float16* mSp  = (const _Float16*)mS + (size_t)(i0 + mr) * NN + j0 + grp * 8;

  f32x4 accD = {0.f,0.f,0.f,0.f}, accS = {0.f,0.f,0.f,0.f};
  f32x4 dnD  = {0.f,0.f,0.f,0.f}, dnS  = {0.f,0.f,0.f,0.f};

  #pragma unroll 4
  for (int it = 0; it < CHUNK / 32; ++it) {
    const h16x8 e1 = *(const h16x8*)(e1p_ + it * 32);
    const h16x8 e3 = *(const h16x8*)(e3p_ + it * 32);
    const h16x8 sv = *(const h16x8*)(scp_ + it * 32);
    const h16x8 md = *(const h16x8*)(mDp + it * 32);
    const h16x8 ms = *(const h16x8*)(mSp + it * 32);

    const h16x8 q = __builtin_elementwise_max(e1 * af8, e3 * bf8);
    const h16x8 eD = q * md;
    const h16x8 eS = q * ms;

    accD = __builtin_amdgcn_mfma_f32_16x16x32_f16(eD, sv, accD, 0, 0, 0);
    accS = __builtin_amdgcn_mfma_f32_16x16x32_f16(eS, sv, accS, 0, 0, 0);
    dnD  = __builtin_amdgcn_mfma_f32_16x16x32_f16(eD, ones, dnD, 0, 0, 0);
    dnS  = __builtin_amdgcn_mfma_f32_16x16x32_f16(eS, ones, dnS, 0, 0, 0);
  }

  // partials: pn[((c*256+t)*8+h)*2+g][row][col], pd[((c*256+t)*8+h)*2+g][row]
  float* pnb = pn + ((((size_t)c * 256 + t) * 8 + h) * 2) * 256;
  #pragma unroll
  for (int r = 0; r < 4; ++r) {
    const int row = grp * 4 + r;
    pnb[row * 16 + mr]       = accD[r];
    pnb[256 + row * 16 + mr] = accS[r];
  }
  if (mr == 0) {
    float* pdb = pd + ((((size_t)c * 256 + t) * 8 + h) * 2) * 16;
    #pragma unroll
    for (int r = 0; r < 4; ++r) {
      pdb[grp * 4 + r]      = dnD[r];
      pdb[16 + grp * 4 + r] = dnS[r];
    }
  }
}

// ---- K3: reduce partials, normalize, output GEMM. grid 256 x 512 ----
__global__ __launch_bounds__(512) void k_reduce(
    const float* __restrict__ pn, const float* __restrict__ pd,
    const unsigned short* __restrict__ Xb, const unsigned short* __restrict__ WpT,
    const float* __restrict__ bsum, float* __restrict__ out)
{
  __shared__ unsigned short catT[16][520];  // [row][ S(128) | D(128) | X(256) ]
  const int t = blockIdx.x, i0 = t * 16;
  const int tid = threadIdx.x;
  {  // stage X rows -> catT cols 256..511
    const int r = tid >> 5, x0 = (tid & 31) * 8;
    *(bf16x8*)(&catT[r][256 + x0]) = *(const bf16x8*)(Xb + (size_t)(i0 + r) * 256 + x0);
  }
  const int h = tid >> 6, lane = tid & 63;
  const int mr = lane & 15, grp = lane >> 4;

  #pragma unroll
  for (int r = 0; r < 4; ++r) {
    const int row = grp * 4 + r;
    float vD = 0.f, vS = 0.f, dD = 0.f, dS = 0.f;
    #pragma unroll
    for (int c = 0; c < NS; ++c) {
      const size_t nb = ((((size_t)c * 256 + t) * 8 + h) * 2) * 256;
      const size_t db = ((((size_t)c * 256 + t) * 8 + h) * 2) * 16;
      vD += pn[nb + row * 16 + mr];
      vS += pn[nb + 256 + row * 16 + mr];
      dD += pd[db + row];
      dS += pd[db + 16 + row];
    }
    const float oS = vS * __builtin_amdgcn_rcpf(fmaxf(dS, 1e-30f));
    const float oD = vD * __builtin_amdgcn_rcpf(fmaxf(dD, 1e-30f));
    catT[row][h * 16 + mr]       = f2bf_rn(oS);
    catT[row][128 + h * 16 + mr] = f2bf_rn(oD);
  }
  __syncthreads();

  // phase B: out[16][128] = catT[16][512] @ W'[512][128] + bsum
  f32x4 o = {0.f, 0.f, 0.f, 0.f};
  const unsigned short* wp = WpT + (size_t)(h * 16 + mr) * 512;
  #pragma unroll
  for (int ks = 0; ks < 16; ++ks) {
    bf16x8 a = *(const bf16x8*)(&catT[mr][ks * 32 + grp * 8]);
    bf16x8 b = *(const bf16x8*)(wp + ks * 32 + grp * 8);
    o = __builtin_amdgcn_mfma_f32_16x16x32_bf16(a, b, o, 0, 0, 0);
  }
  const float bs = bsum[h * 16 + mr];
  #pragma unroll
  for (int r = 0; r < 4; ++r)
    out[(size_t)(i0 + grp * 4 + r) * 128 + h * 16 + mr] = o[r] + bs;
}

extern "C" void kernel_launch(void* const* d_in, const int* in_sizes, int n_in,
                              void* d_out, int out_size, void* d_ws, size_t ws_size,
                              hipStream_t stream) {
  const float* X    = (const float*)d_in[0];
  const float* Dg   = (const float*)d_in[1];
  const float* Sg   = (const float*)d_in[2];
  const float* Ww   = (const float*)d_in[3];
  const float* Wb   = (const float*)d_in[4];
  const float* wu   = (const float*)d_in[5];
  const float* wv   = (const float*)d_in[6];
  const float* Wcat = (const float*)d_in[7];
  const float* Wcb  = (const float*)d_in[8];
  const float* bias = (const float*)d_in[9];
  const float* proj = (const float*)d_in[10];
  const float* prb  = (const float*)d_in[11];
  float* out = (float*)d_out;

  char* ws = (char*)d_ws;
  unsigned short* Xb   = (unsigned short*)(ws);               // 2 MB
  unsigned short* scT  = (unsigned short*)(ws + 0x200000);    // 1 MB (f16)
  float*          f2   = (float*)(ws + 0x300000);             // 128 KB
  unsigned short* E1p  = (unsigned short*)(ws + 0x320000);    // 64 KB (f16)
  unsigned short* E3p  = (unsigned short*)(ws + 0x330000);    // 64 KB (f16)
  unsigned short* WwT  = (unsigned short*)(ws + 0x340000);    // 64 KB
  unsigned short* WpT  = (unsigned short*)(ws + 0x350000);    // 128 KB
  float*          bsum = (float*)(ws + 0x370000);             // 512 B
  unsigned short* mD   = (unsigned short*)(ws + 0x400000);    // 32 MB (f16 masks)
  unsigned short* mS   = (unsigned short*)(ws + 0x2400000);   // 32 MB
  float*          pn   = (float*)(ws + 0x4400000);            // 16 MB
  float*          pd   = (float*)(ws + 0x5400000);            // 1 MB

  k_prep<<<dim3(512), dim3(256), 0, stream>>>(X, Ww, Wcat, proj, Wcb, bias, prb,
                                              Xb, WwT, WpT, bsum);
  k_cvt<<<dim3(16384), dim3(256), 0, stream>>>(Dg, Sg, mD, mS);
  k_score<<<dim3(256), dim3(512), 0, stream>>>(Xb, WwT, Wb, wu, wv, scT, f2, E1p, E3p);
  k_attn<<<dim3(NS * 256), dim3(512), 0, stream>>>(mD, mS, scT, E1p, E3p, f2, pn, pd);
  k_reduce<<<dim3(256), dim3(512), 0, stream>>>(pn, pd, Xb, WpT, bsum, out);
}

// Round 17
// 102.068 us; speedup vs baseline: 1.6492x; 1.6492x over previous
//
#include <hip/hip_runtime.h>
#include <hip/hip_bf16.h>

// GAT MultiHeads, MI355X. N=4096, F_IN=256, H=8, D=16, HD=128.
// All inputs/outputs f32; attention inner loop packed f16 + LDS byte-masks.
//
// Math identities (vs reference):
//  - logits[h,i,j] = f1[h,j] + f2[h,i]  (rank-1, never materialized)
//  - exp(lrelu(x)) = max(e^x, e^{0.3x})  (exp monotone, lrelu = max(x,0.3x))
//    => q = max(E1[j]*A[i], E3[j]*B[i]); E1=e^f1, E3=e^{0.3f1}, A=e^f2, B=e^{0.3f2}
//  - no max-subtraction: logits bounded (|x| < ~5), softmax ratio invariant
//  - g in {0,1} => mask as byte 0x00/0xFF; applied to packed-f16 q via
//    v_perm (byte->16-bit replicate) + v_and  (exact, 2 ops/pair)
//  - denominators = P @ ones via MFMA (idle pipe), lane gets its row sum
//  - fully-masked rows: denom clamp 1e-30 => output row 0 (matches densify)
//
// Pipeline: k_prep (cvt weights/X) / k_cvt (masks f32 -> bytes, dedicated
// full-BW streaming kernel: 134MB read + 32MB write = the unavoidable floor) /
// k_score (score GEMM + f16 exp tables) / k_attn (j-split x4; per block stage
// 32KB byte-masks -> LDS once, ONE barrier; inner loop: 2 ds_read_b64 +
// 3 L2-resident table loads + ~32 VALU + 4 MFMA) / k_reduce (sum + out GEMM).

#define NN 4096
#define LOG2E 1.44269504088896340736f
#define NS 4          // j-split chunks
#define CHUNK 1024    // NN/NS

typedef short bf16x8 __attribute__((ext_vector_type(8)));
typedef float f32x4  __attribute__((ext_vector_type(4)));
typedef _Float16 h16x8 __attribute__((ext_vector_type(8)));
typedef __fp16  fp16x2 __attribute__((ext_vector_type(2)));

union hu8 { unsigned int u[4]; h16x8 v; };

__device__ __forceinline__ unsigned short f2bf_rn(float f) {
  union { float f; unsigned int i; } v; v.f = f;
  unsigned int r = v.i + 0x7FFFu + ((v.i >> 16) & 1u);  // RTNE
  return (unsigned short)(r >> 16);
}
// two f32 -> packed 2x f16 (RTZ) as u32
__device__ __forceinline__ unsigned int pk2(float lo, float hi) {
  fp16x2 h = __builtin_amdgcn_cvt_pkrtz(lo, hi);
  union { fp16x2 h; unsigned int u; } v; v.h = h; return v.u;
}

// ---- K0: one-time conversions. grid 512x256 ----
__global__ __launch_bounds__(256) void k_prep(
    const float* __restrict__ X, const float* __restrict__ Ww,
    const float* __restrict__ Wcat, const float* __restrict__ proj,
    const float* __restrict__ Wcb, const float* __restrict__ bias,
    const float* __restrict__ prb,
    unsigned short* __restrict__ Xb, unsigned short* __restrict__ WwT,
    unsigned short* __restrict__ WpT, float* __restrict__ bsum)
{
  const int tid = blockIdx.x * 256 + threadIdx.x;  // 0..131071
  {  // X[4096][256] f32 -> bf16 (RTNE), 8 elements/thread
    const float4 a = *(const float4*)(X + (size_t)tid * 8);
    const float4 b = *(const float4*)(X + (size_t)tid * 8 + 4);
    uint4 o;
    o.x = (unsigned)f2bf_rn(a.x) | ((unsigned)f2bf_rn(a.y) << 16);
    o.y = (unsigned)f2bf_rn(a.z) | ((unsigned)f2bf_rn(a.w) << 16);
    o.z = (unsigned)f2bf_rn(b.x) | ((unsigned)f2bf_rn(b.y) << 16);
    o.w = (unsigned)f2bf_rn(b.z) | ((unsigned)f2bf_rn(b.w) << 16);
    *(uint4*)(Xb + (size_t)tid * 8) = o;
  }
  if (tid < 32768) {  // WwT[c][k] = Ww[k][c], bf16
    int c = tid & 127, k = tid >> 7;
    WwT[c * 256 + k] = f2bf_rn(Ww[k * 128 + c]);
  }
  if (tid < 65536) {  // WpT[c][k]: k<256 -> Wcat[k][c], else proj[k-256][c]
    int c = tid & 127, k = tid >> 7;
    float v = (k < 256) ? Wcat[k * 128 + c] : proj[(k - 256) * 128 + c];
    WpT[c * 512 + k] = f2bf_rn(v);
  }
  if (tid < 128) bsum[tid] = Wcb[tid] + bias[tid] + prb[tid];
}

// ---- K0b: masks f32 -> bytes (0x00/0xFF), pure streaming. grid 16384x256 ----
// 8 elements/thread: read 32B coalesced, write 8B coalesced.
__global__ __launch_bounds__(256) void k_cvt(
    const float* __restrict__ Dg, const float* __restrict__ Sg,
    unsigned char* __restrict__ bD8, unsigned char* __restrict__ bS8)
{
  const size_t tid = (size_t)blockIdx.x * 256 + threadIdx.x;  // 0..4194303
  const int g = (int)(tid >> 21);            // 2,097,152 threads per graph
  const float* src = g ? Sg : Dg;
  unsigned char* dst = g ? bS8 : bD8;
  const size_t off = (tid & 0x1FFFFFull) * 8;
  const float4 a = *(const float4*)(src + off);
  const float4 b = *(const float4*)(src + off + 4);
  uint2 o;
  o.x = (a.x != 0.f ? 0x000000FFu : 0u) | (a.y != 0.f ? 0x0000FF00u : 0u)
      | (a.z != 0.f ? 0x00FF0000u : 0u) | (a.w != 0.f ? 0xFF000000u : 0u);
  o.y = (b.x != 0.f ? 0x000000FFu : 0u) | (b.y != 0.f ? 0x0000FF00u : 0u)
      | (b.z != 0.f ? 0x00FF0000u : 0u) | (b.w != 0.f ? 0xFF000000u : 0u);
  *(uint2*)(dst + off) = o;
}

// ---- K1: score GEMM + f2 + f16 exp tables. grid 256 x 512 ----
__global__ __launch_bounds__(512) void k_score(
    const unsigned short* __restrict__ Xb, const unsigned short* __restrict__ WwT,
    const float* __restrict__ Wb, const float* __restrict__ wu,
    const float* __restrict__ wv,
    unsigned short* __restrict__ scT, float* __restrict__ f2,
    unsigned short* __restrict__ E1p, unsigned short* __restrict__ E3p)
{
  const int n0 = blockIdx.x * 16;
  const int h = threadIdx.x >> 6, lane = threadIdx.x & 63;
  const int mr = lane & 15, grp = lane >> 4;
  const unsigned short* ap  = Xb  + (size_t)(n0 + mr) * 256;
  const unsigned short* bpp = WwT + (size_t)(h * 16 + mr) * 256;
  f32x4 acc = {0.f, 0.f, 0.f, 0.f};
  #pragma unroll
  for (int ks = 0; ks < 8; ++ks) {
    bf16x8 a = *(const bf16x8*)(ap  + ks * 32 + grp * 8);
    bf16x8 b = *(const bf16x8*)(bpp + ks * 32 + grp * 8);
    acc = __builtin_amdgcn_mfma_f32_16x16x32_bf16(a, b, acc, 0, 0, 0);
  }
  const float wb = Wb[h * 16 + mr];
  float sc[4];
  #pragma unroll
  for (int r = 0; r < 4; ++r) sc[r] = acc[r] + wb;  // score[n0+grp*4+r][h*16+mr]

  {  // scT[h*16+mr][n0+grp*4 .. +3] f16
    uint2 st;
    st.x = pk2(sc[0], sc[1]);
    st.y = pk2(sc[2], sc[3]);
    *(uint2*)(scT + (size_t)(h * 16 + mr) * NN + n0 + grp * 4) = st;
  }

  const float uw = wu[h * 16 + mr], vw = wv[h * 16 + mr];
  float t1[4], t2[4];
  #pragma unroll
  for (int r = 0; r < 4; ++r) { t1[r] = sc[r] * uw; t2[r] = sc[r] * vw; }
  #pragma unroll
  for (int m = 1; m < 16; m <<= 1) {
    #pragma unroll
    for (int r = 0; r < 4; ++r) {
      t1[r] += __shfl_xor(t1[r], m, 64);
      t2[r] += __shfl_xor(t2[r], m, 64);
    }
  }
  if (mr == 0) {
    *(float4*)(f2 + h * NN + n0 + grp * 4) = make_float4(t2[0], t2[1], t2[2], t2[3]);
    float e1[4], e3[4];
    #pragma unroll
    for (int r = 0; r < 4; ++r) {
      e1[r] = __builtin_amdgcn_exp2f(t1[r] * LOG2E);
      e3[r] = __builtin_amdgcn_exp2f(0.3f * t1[r] * LOG2E);
    }
    uint2 p1, p3;
    p1.x = pk2(e1[0], e1[1]);
    p1.y = pk2(e1[2], e1[3]);
    p3.x = pk2(e3[0], e3[1]);
    p3.y = pk2(e3[2], e3[3]);
    *(uint2*)(E1p + h * NN + n0 + grp * 4) = p1;
    *(uint2*)(E3p + h * NN + n0 + grp * 4) = p3;
  }
}

// ---- K2: dual-graph masked softmax attention, j-split x NS ----
// grid = NS*256 (bx = chunk*256 + tile), 512 thr (8 waves = 8 heads).
// Byte-masks (32KB/block) staged to LDS once (16B-XOR swizzle both sides,
// one barrier). Inner loop: 2 ds_read_b64 + 3 L2-table loads + perm/and
// expansion + 4 MFMA. No scalar loads, no in-loop barriers.
__global__ __launch_bounds__(512, 8) void k_attn(
    const unsigned char* __restrict__ bD8, const unsigned char* __restrict__ bS8,
    const unsigned short* __restrict__ scT, const unsigned short* __restrict__ E1p,
    const unsigned short* __restrict__ E3p, const float* __restrict__ f2,
    float* __restrict__ pn, float* __restrict__ pd)
{
  __shared__ __align__(16) unsigned char mlds[2][16][1024];  // 32 KB
  const int bx = blockIdx.x;
  const int c = bx >> 8, t = bx & 255;
  const int i0 = t << 4, j0 = c * CHUNK;
  const int tid = threadIdx.x;

  {  // stage this block's byte-masks: 2 graphs x 16 rows x 1024 cols
    const int sg = tid >> 8, sr = (tid >> 4) & 15, ss = tid & 15;
    const unsigned char* src = (sg ? bS8 : bD8) + (size_t)(i0 + sr) * NN + j0 + ss * 64;
    unsigned char* base = &mlds[sg][sr][0];
    const int swzw = (sr & 7) << 4;
    #pragma unroll
    for (int i = 0; i < 4; ++i) {
      const uint4 v = *(const uint4*)(src + i * 16);
      *(uint4*)(base + ((ss * 64 + i * 16) ^ swzw)) = v;
    }
  }
  __syncthreads();

  const int h = tid >> 6, lane = tid & 63;
  const int mr = lane & 15, grp = lane >> 4;

  const float f2v = f2[h * NN + i0 + mr];
  const _Float16 afh = (_Float16)__builtin_amdgcn_exp2f(f2v * LOG2E);
  const _Float16 bfh = (_Float16)__builtin_amdgcn_exp2f(0.3f * f2v * LOG2E);
  const h16x8 af8 = {afh, afh, afh, afh, afh, afh, afh, afh};
  const h16x8 bf8 = {bfh, bfh, bfh, bfh, bfh, bfh, bfh, bfh};
  const _Float16 one = (_Float16)1.f;
  const h16x8 ones = {one, one, one, one, one, one, one, one};

  const _Float16* e1p_ = (const _Float16*)E1p + h * NN + j0 + grp * 8;
  const _Float16* e3p_ = (const _Float16*)E3p + h * NN + j0 + grp * 8;
  const _Float16* scp_ = (const _Float16*)scT + (size_t)(h * 16 + mr) * NN + j0 + grp * 8;

  // LDS mask read address: ((it*32 + (grp>>1)*16) ^ ((mr&7)<<4)) + (grp&1)*8
  const int swz = (mr & 7) << 4;
  const int gsub = (grp >> 1) * 16, goff = (grp & 1) * 8;
  const unsigned char* mdL = &mlds[0][mr][0];
  const unsigned char* msL = &mlds[1][mr][0];

  f32x4 accD = {0.f,0.f,0.f,0.f}, accS = {0.f,0.f,0.f,0.f};
  f32x4 dnD  = {0.f,0.f,0.f,0.f}, dnS  = {0.f,0.f,0.f,0.f};

  #pragma unroll 4
  for (int it = 0; it < CHUNK / 32; ++it) {
    const int moff = (((it * 32 + gsub) ^ swz) + goff);
    const uint2 wd = *(const uint2*)(mdL + moff);   // ds_read_b64: bytes e0..e7
    const uint2 ws = *(const uint2*)(msL + moff);
    const h16x8 e1 = *(const h16x8*)(e1p_ + it * 32);
    const h16x8 e3 = *(const h16x8*)(e3p_ + it * 32);
    const h16x8 sv = *(const h16x8*)(scp_ + it * 32);

    hu8 Q, AD, AS;
    Q.v = __builtin_elementwise_max(e1 * af8, e3 * bf8);
    // byte -> 16-bit replicated AND-mask: one v_perm + one v_and per pair
    AD.u[0] = Q.u[0] & __builtin_amdgcn_perm(0u, wd.x, 0x01010000u);
    AD.u[1] = Q.u[1] & __builtin_amdgcn_perm(0u, wd.x, 0x03030202u);
    AD.u[2] = Q.u[2] & __builtin_amdgcn_perm(0u, wd.y, 0x01010000u);
    AD.u[3] = Q.u[3] & __builtin_amdgcn_perm(0u, wd.y, 0x03030202u);
    AS.u[0] = Q.u[0] & __builtin_amdgcn_perm(0u, ws.x, 0x01010000u);
    AS.u[1] = Q.u[1] & __builtin_amdgcn_perm(0u, ws.x, 0x03030202u);
    AS.u[2] = Q.u[2] & __builtin_amdgcn_perm(0u, ws.y, 0x01010000u);
    AS.u[3] = Q.u[3] & __builtin_amdgcn_perm(0u, ws.y, 0x03030202u);

    accD = __builtin_amdgcn_mfma_f32_16x16x32_f16(AD.v, sv, accD, 0, 0, 0);
    accS = __builtin_amdgcn_mfma_f32_16x16x32_f16(AS.v, sv, accS, 0, 0, 0);
    dnD  = __builtin_amdgcn_mfma_f32_16x16x32_f16(AD.v, ones, dnD, 0, 0, 0);
    dnS  = __builtin_amdgcn_mfma_f32_16x16x32_f16(AS.v, ones, dnS, 0, 0, 0);
  }

  // partials: pn[((c*256+t)*8+h)*2+g][row][col], pd[((c*256+t)*8+h)*2+g][row]
  float* pnb = pn + ((((size_t)c * 256 + t) * 8 + h) * 2) * 256;
  #pragma unroll
  for (int r = 0; r < 4; ++r) {
    const int row = grp * 4 + r;
    pnb[row * 16 + mr]       = accD[r];
    pnb[256 + row * 16 + mr] = accS[r];
  }
  if (mr == 0) {
    float* pdb = pd + ((((size_t)c * 256 + t) * 8 + h) * 2) * 16;
    #pragma unroll
    for (int r = 0; r < 4; ++r) {
      pdb[grp * 4 + r]      = dnD[r];
      pdb[16 + grp * 4 + r] = dnS[r];
    }
  }
}

// ---- K3: reduce partials, normalize, output GEMM. grid 256 x 512 ----
__global__ __launch_bounds__(512) void k_reduce(
    const float* __restrict__ pn, const float* __restrict__ pd,
    const unsigned short* __restrict__ Xb, const unsigned short* __restrict__ WpT,
    const float* __restrict__ bsum, float* __restrict__ out)
{
  __shared__ unsigned short catT[16][520];  // [row][ S(128) | D(128) | X(256) ]
  const int t = blockIdx.x, i0 = t * 16;
  const int tid = threadIdx.x;
  {  // stage X rows -> catT cols 256..511
    const int r = tid >> 5, x0 = (tid & 31) * 8;
    *(bf16x8*)(&catT[r][256 + x0]) = *(const bf16x8*)(Xb + (size_t)(i0 + r) * 256 + x0);
  }
  const int h = tid >> 6, lane = tid & 63;
  const int mr = lane & 15, grp = lane >> 4;

  #pragma unroll
  for (int r = 0; r < 4; ++r) {
    const int row = grp * 4 + r;
    float vD = 0.f, vS = 0.f, dD = 0.f, dS = 0.f;
    #pragma unroll
    for (int c = 0; c < NS; ++c) {
      const size_t nb = ((((size_t)c * 256 + t) * 8 + h) * 2) * 256;
      const size_t db = ((((size_t)c * 256 + t) * 8 + h) * 2) * 16;
      vD += pn[nb + row * 16 + mr];
      vS += pn[nb + 256 + row * 16 + mr];
      dD += pd[db + row];
      dS += pd[db + 16 + row];
    }
    const float oS = vS * __builtin_amdgcn_rcpf(fmaxf(dS, 1e-30f));
    const float oD = vD * __builtin_amdgcn_rcpf(fmaxf(dD, 1e-30f));
    catT[row][h * 16 + mr]       = f2bf_rn(oS);
    catT[row][128 + h * 16 + mr] = f2bf_rn(oD);
  }
  __syncthreads();

  // phase B: out[16][128] = catT[16][512] @ W'[512][128] + bsum
  f32x4 o = {0.f, 0.f, 0.f, 0.f};
  const unsigned short* wp = WpT + (size_t)(h * 16 + mr) * 512;
  #pragma unroll
  for (int ks = 0; ks < 16; ++ks) {
    bf16x8 a = *(const bf16x8*)(&catT[mr][ks * 32 + grp * 8]);
    bf16x8 b = *(const bf16x8*)(wp + ks * 32 + grp * 8);
    o = __builtin_amdgcn_mfma_f32_16x16x32_bf16(a, b, o, 0, 0, 0);
  }
  const float bs = bsum[h * 16 + mr];
  #pragma unroll
  for (int r = 0; r < 4; ++r)
    out[(size_t)(i0 + grp * 4 + r) * 128 + h * 16 + mr] = o[r] + bs;
}

extern "C" void kernel_launch(void* const* d_in, const int* in_sizes, int n_in,
                              void* d_out, int out_size, void* d_ws, size_t ws_size,
                              hipStream_t stream) {
  const float* X    = (const float*)d_in[0];
  const float* Dg   = (const float*)d_in[1];
  const float* Sg   = (const float*)d_in[2];
  const float* Ww   = (const float*)d_in[3];
  const float* Wb   = (const float*)d_in[4];
  const float* wu   = (const float*)d_in[5];
  const float* wv   = (const float*)d_in[6];
  const float* Wcat = (const float*)d_in[7];
  const float* Wcb  = (const float*)d_in[8];
  const float* bias = (const float*)d_in[9];
  const float* proj = (const float*)d_in[10];
  const float* prb  = (const float*)d_in[11];
  float* out = (float*)d_out;

  char* ws = (char*)d_ws;
  unsigned short* Xb   = (unsigned short*)(ws);               // 2 MB
  unsigned short* scT  = (unsigned short*)(ws + 0x200000);    // 1 MB (f16)
  float*          f2   = (float*)(ws + 0x300000);             // 128 KB
  unsigned short* E1p  = (unsigned short*)(ws + 0x320000);    // 64 KB (f16)
  unsigned short* E3p  = (unsigned short*)(ws + 0x330000);    // 64 KB (f16)
  unsigned short* WwT  = (unsigned short*)(ws + 0x340000);    // 64 KB
  unsigned short* WpT  = (unsigned short*)(ws + 0x350000);    // 128 KB
  float*          bsum = (float*)(ws + 0x370000);             // 512 B
  unsigned char*  bD8  = (unsigned char*)(ws + 0x400000);     // 16 MB byte masks
  unsigned char*  bS8  = (unsigned char*)(ws + 0x1400000);    // 16 MB
  float*          pn   = (float*)(ws + 0x2400000);            // 16 MB
  float*          pd   = (float*)(ws + 0x3400000);            // 1 MB

  k_prep<<<dim3(512), dim3(256), 0, stream>>>(X, Ww, Wcat, proj, Wcb, bias, prb,
                                              Xb, WwT, WpT, bsum);
  k_cvt<<<dim3(16384), dim3(256), 0, stream>>>(Dg, Sg, bD8, bS8);
  k_score<<<dim3(256), dim3(512), 0, stream>>>(Xb, WwT, Wb, wu, wv, scT, f2, E1p, E3p);
  k_attn<<<dim3(NS * 256), dim3(512), 0, stream>>>(bD8, bS8, scT, E1p, E3p, f2, pn, pd);
  k_reduce<<<dim3(256), dim3(512), 0, stream>>>(pn, pd, Xb, WpT, bsum, out);
}

// Round 18
// 100.929 us; speedup vs baseline: 1.6678x; 1.0113x over previous
//
#include <hip/hip_runtime.h>
#include <hip/hip_bf16.h>

// GAT MultiHeads, MI355X. N=4096, F_IN=256, H=8, D=16, HD=128.
// All inputs/outputs f32; attention inner loop packed f16 + LDS byte-masks.
//
// Math identities (vs reference):
//  - logits[h,i,j] = f1[h,j] + f2[h,i]  (rank-1, never materialized)
//  - exp(lrelu(x)) = max(e^x, e^{0.3x})  (exp monotone, lrelu = max(x,0.3x))
//    => q = max(E1[j]*A[i], E3[j]*B[i]); E1=e^f1, E3=e^{0.3f1}, A=e^f2, B=e^{0.3f2}
//  - no max-subtraction: logits bounded (|x| < ~5), softmax ratio invariant
//  - g in {0,1} => mask as byte 0x00/0xFF; applied to packed-f16 q via
//    v_perm (byte->16-bit replicate) + v_and  (exact, 2 ops/pair)
//  - denominators: v_dot2_f32_f16(masked pair, {1,1}) per lane (partial row
//    sum over this lane's k-slice) + 2 shfl_xor epilogue reduction
//  - fully-masked rows: denom clamp 1e-30 => output row 0 (matches densify)
//
// Pipeline: k_prep / k_cvt (masks f32 -> INTERLEAVED [D8|S8] bytes; the 134MB
// HBM floor pass) / k_score / k_attn (j-split x4; 32KB mask bytes -> padded
// LDS once, ONE barrier; inner loop: 3 global streams + 1 ds_read_b128 +
// ~40 VALU + 2 MFMA) / k_reduce.

#define NN 4096
#define LOG2E 1.44269504088896340736f
#define NS 4          // j-split chunks
#define CHUNK 1024    // NN/NS
#define MROW 2064     // LDS mask row bytes: 2048 + 16 pad (bank balance)

typedef short bf16x8 __attribute__((ext_vector_type(8)));
typedef float f32x4  __attribute__((ext_vector_type(4)));
typedef _Float16 h16x8 __attribute__((ext_vector_type(8)));
typedef _Float16 h16x2 __attribute__((ext_vector_type(2)));
typedef __fp16  fp16x2 __attribute__((ext_vector_type(2)));

union hu8 { unsigned int u[4]; h16x8 v; };
union hu2 { unsigned int u; h16x2 h; };

__device__ __forceinline__ unsigned short f2bf_rn(float f) {
  union { float f; unsigned int i; } v; v.f = f;
  unsigned int r = v.i + 0x7FFFu + ((v.i >> 16) & 1u);  // RTNE
  return (unsigned short)(r >> 16);
}
// two f32 -> packed 2x f16 (RTZ) as u32
__device__ __forceinline__ unsigned int pk2(float lo, float hi) {
  fp16x2 h = __builtin_amdgcn_cvt_pkrtz(lo, hi);
  union { fp16x2 h; unsigned int u; } v; v.h = h; return v.u;
}
// dot2 accumulate: acc += pair.x + pair.y (f16 inputs, f32 accumulate)
__device__ __forceinline__ float dot2acc(unsigned int pair, float acc) {
  hu2 p; p.u = pair;
#if __has_builtin(__builtin_amdgcn_fdot2)
  const h16x2 one2 = {(_Float16)1.f, (_Float16)1.f};
  return __builtin_amdgcn_fdot2(p.h, one2, acc, false);
#else
  return acc + (float)p.h.x + (float)p.h.y;
#endif
}
__device__ __forceinline__ unsigned int bytesel(float4 a) {
  return (a.x != 0.f ? 0x000000FFu : 0u) | (a.y != 0.f ? 0x0000FF00u : 0u)
       | (a.z != 0.f ? 0x00FF0000u : 0u) | (a.w != 0.f ? 0xFF000000u : 0u);
}

// ---- K0: one-time conversions. grid 512x256 ----
__global__ __launch_bounds__(256) void k_prep(
    const float* __restrict__ X, const float* __restrict__ Ww,
    const float* __restrict__ Wcat, const float* __restrict__ proj,
    const float* __restrict__ Wcb, const float* __restrict__ bias,
    const float* __restrict__ prb,
    unsigned short* __restrict__ Xb, unsigned short* __restrict__ WwT,
    unsigned short* __restrict__ WpT, float* __restrict__ bsum)
{
  const int tid = blockIdx.x * 256 + threadIdx.x;  // 0..131071
  {  // X[4096][256] f32 -> bf16 (RTNE), 8 elements/thread
    const float4 a = *(const float4*)(X + (size_t)tid * 8);
    const float4 b = *(const float4*)(X + (size_t)tid * 8 + 4);
    uint4 o;
    o.x = (unsigned)f2bf_rn(a.x) | ((unsigned)f2bf_rn(a.y) << 16);
    o.y = (unsigned)f2bf_rn(a.z) | ((unsigned)f2bf_rn(a.w) << 16);
    o.z = (unsigned)f2bf_rn(b.x) | ((unsigned)f2bf_rn(b.y) << 16);
    o.w = (unsigned)f2bf_rn(b.z) | ((unsigned)f2bf_rn(b.w) << 16);
    *(uint4*)(Xb + (size_t)tid * 8) = o;
  }
  if (tid < 32768) {  // WwT[c][k] = Ww[k][c], bf16
    int c = tid & 127, k = tid >> 7;
    WwT[c * 256 + k] = f2bf_rn(Ww[k * 128 + c]);
  }
  if (tid < 65536) {  // WpT[c][k]: k<256 -> Wcat[k][c], else proj[k-256][c]
    int c = tid & 127, k = tid >> 7;
    float v = (k < 256) ? Wcat[k * 128 + c] : proj[(k - 256) * 128 + c];
    WpT[c * 512 + k] = f2bf_rn(v);
  }
  if (tid < 128) bsum[tid] = Wcb[tid] + bias[tid] + prb[tid];
}

// ---- K0b: masks f32 -> interleaved bytes [row][j8][D0..7|S0..7]. ----
// grid 8192x256; 8 j per thread: read 2x32B (D,S), write one 16B uint4.
__global__ __launch_bounds__(256) void k_cvt(
    const float* __restrict__ Dg, const float* __restrict__ Sg,
    unsigned char* __restrict__ mDS)
{
  const size_t tid = (size_t)blockIdx.x * 256 + threadIdx.x;  // 0..2097151
  const size_t off = tid * 8;
  const float4 da = *(const float4*)(Dg + off);
  const float4 db = *(const float4*)(Dg + off + 4);
  const float4 sa = *(const float4*)(Sg + off);
  const float4 sb = *(const float4*)(Sg + off + 4);
  uint4 o;
  o.x = bytesel(da); o.y = bytesel(db);
  o.z = bytesel(sa); o.w = bytesel(sb);
  *(uint4*)(mDS + tid * 16) = o;
}

// ---- K1: score GEMM + f2 + f16 exp tables. grid 256 x 512 ----
__global__ __launch_bounds__(512) void k_score(
    const unsigned short* __restrict__ Xb, const unsigned short* __restrict__ WwT,
    const float* __restrict__ Wb, const float* __restrict__ wu,
    const float* __restrict__ wv,
    unsigned short* __restrict__ scT, float* __restrict__ f2,
    unsigned short* __restrict__ E1p, unsigned short* __restrict__ E3p)
{
  const int n0 = blockIdx.x * 16;
  const int h = threadIdx.x >> 6, lane = threadIdx.x & 63;
  const int mr = lane & 15, grp = lane >> 4;
  const unsigned short* ap  = Xb  + (size_t)(n0 + mr) * 256;
  const unsigned short* bpp = WwT + (size_t)(h * 16 + mr) * 256;
  f32x4 acc = {0.f, 0.f, 0.f, 0.f};
  #pragma unroll
  for (int ks = 0; ks < 8; ++ks) {
    bf16x8 a = *(const bf16x8*)(ap  + ks * 32 + grp * 8);
    bf16x8 b = *(const bf16x8*)(bpp + ks * 32 + grp * 8);
    acc = __builtin_amdgcn_mfma_f32_16x16x32_bf16(a, b, acc, 0, 0, 0);
  }
  const float wb = Wb[h * 16 + mr];
  float sc[4];
  #pragma unroll
  for (int r = 0; r < 4; ++r) sc[r] = acc[r] + wb;  // score[n0+grp*4+r][h*16+mr]

  {  // scT[h*16+mr][n0+grp*4 .. +3] f16
    uint2 st;
    st.x = pk2(sc[0], sc[1]);
    st.y = pk2(sc[2], sc[3]);
    *(uint2*)(scT + (size_t)(h * 16 + mr) * NN + n0 + grp * 4) = st;
  }

  const float uw = wu[h * 16 + mr], vw = wv[h * 16 + mr];
  float t1[4], t2[4];
  #pragma unroll
  for (int r = 0; r < 4; ++r) { t1[r] = sc[r] * uw; t2[r] = sc[r] * vw; }
  #pragma unroll
  for (int m = 1; m < 16; m <<= 1) {
    #pragma unroll
    for (int r = 0; r < 4; ++r) {
      t1[r] += __shfl_xor(t1[r], m, 64);
      t2[r] += __shfl_xor(t2[r], m, 64);
    }
  }
  if (mr == 0) {
    *(float4*)(f2 + h * NN + n0 + grp * 4) = make_float4(t2[0], t2[1], t2[2], t2[3]);
    float e1[4], e3[4];
    #pragma unroll
    for (int r = 0; r < 4; ++r) {
      e1[r] = __builtin_amdgcn_exp2f(t1[r] * LOG2E);
      e3[r] = __builtin_amdgcn_exp2f(0.3f * t1[r] * LOG2E);
    }
    uint2 p1, p3;
    p1.x = pk2(e1[0], e1[1]);
    p1.y = pk2(e1[2], e1[3]);
    p3.x = pk2(e3[0], e3[1]);
    p3.y = pk2(e3[2], e3[3]);
    *(uint2*)(E1p + h * NN + n0 + grp * 4) = p1;
    *(uint2*)(E3p + h * NN + n0 + grp * 4) = p3;
  }
}

// ---- K2: dual-graph masked softmax attention, j-split x NS ----
// grid = NS*256 (bx = chunk*256 + tile), 512 thr (8 waves = 8 heads).
// Interleaved byte-masks (32KB/block) staged to padded LDS once (one
// barrier). Inner loop: 3 global streams + ONE ds_read_b128 + ~40 VALU
// + 2 MFMA. Denominators via v_dot2_f32_f16 (no extra MFMA/AGPR).
__global__ __launch_bounds__(512, 8) void k_attn(
    const unsigned char* __restrict__ mDS,
    const unsigned short* __restrict__ scT, const unsigned short* __restrict__ E1p,
    const unsigned short* __restrict__ E3p, const float* __restrict__ f2,
    float* __restrict__ pn, float* __restrict__ pd)
{
  __shared__ __align__(16) unsigned char mlds[16][MROW];  // ~32.3 KB
  const int bx = blockIdx.x;
  const int c = bx >> 8, t = bx & 255;
  const int i0 = t << 4, j0 = c * CHUNK;
  const int tid = threadIdx.x;

  {  // stage: 16 rows x 2048 B (this block's chunk of mDS), 64 B/thread
    const int sr = tid >> 5, ss = tid & 31;
    const unsigned char* src = mDS + (size_t)(i0 + sr) * 8192 + j0 * 2 + ss * 64;
    unsigned char* dst = &mlds[sr][ss * 64];
    #pragma unroll
    for (int i = 0; i < 4; ++i)
      *(uint4*)(dst + i * 16) = *(const uint4*)(src + i * 16);
  }
  __syncthreads();

  const int h = tid >> 6, lane = tid & 63;
  const int mr = lane & 15, grp = lane >> 4;

  const float f2v = f2[h * NN + i0 + mr];
  const _Float16 afh = (_Float16)__builtin_amdgcn_exp2f(f2v * LOG2E);
  const _Float16 bfh = (_Float16)__builtin_amdgcn_exp2f(0.3f * f2v * LOG2E);
  const h16x8 af8 = {afh, afh, afh, afh, afh, afh, afh, afh};
  const h16x8 bf8 = {bfh, bfh, bfh, bfh, bfh, bfh, bfh, bfh};

  const _Float16* e1p_ = (const _Float16*)E1p + h * NN + j0 + grp * 8;
  const _Float16* e3p_ = (const _Float16*)E3p + h * NN + j0 + grp * 8;
  const _Float16* scp_ = (const _Float16*)scT + (size_t)(h * 16 + mr) * NN + j0 + grp * 8;
  const unsigned char* mrow = &mlds[mr][grp * 16];

  f32x4 accD = {0.f,0.f,0.f,0.f}, accS = {0.f,0.f,0.f,0.f};
  float dnD = 0.f, dnS = 0.f;

  #pragma unroll 2
  for (int it = 0; it < CHUNK / 32; ++it) {
    const uint4 m4 = *(const uint4*)(mrow + it * 64);  // D e0-7 | S e0-7
    const h16x8 e1 = *(const h16x8*)(e1p_ + it * 32);
    const h16x8 e3 = *(const h16x8*)(e3p_ + it * 32);
    const h16x8 sv = *(const h16x8*)(scp_ + it * 32);

    hu8 Q, AD, AS;
    Q.v = __builtin_elementwise_max(e1 * af8, e3 * bf8);
    // byte -> 16-bit replicated AND-mask: one v_perm + one v_and per pair
    AD.u[0] = Q.u[0] & __builtin_amdgcn_perm(0u, m4.x, 0x01010000u);
    AD.u[1] = Q.u[1] & __builtin_amdgcn_perm(0u, m4.x, 0x03030202u);
    AD.u[2] = Q.u[2] & __builtin_amdgcn_perm(0u, m4.y, 0x01010000u);
    AD.u[3] = Q.u[3] & __builtin_amdgcn_perm(0u, m4.y, 0x03030202u);
    AS.u[0] = Q.u[0] & __builtin_amdgcn_perm(0u, m4.z, 0x01010000u);
    AS.u[1] = Q.u[1] & __builtin_amdgcn_perm(0u, m4.z, 0x03030202u);
    AS.u[2] = Q.u[2] & __builtin_amdgcn_perm(0u, m4.w, 0x01010000u);
    AS.u[3] = Q.u[3] & __builtin_amdgcn_perm(0u, m4.w, 0x03030202u);

    accD = __builtin_amdgcn_mfma_f32_16x16x32_f16(AD.v, sv, accD, 0, 0, 0);
    accS = __builtin_amdgcn_mfma_f32_16x16x32_f16(AS.v, sv, accS, 0, 0, 0);

    #pragma unroll
    for (int p = 0; p < 4; ++p) {
      dnD = dot2acc(AD.u[p], dnD);
      dnS = dot2acc(AS.u[p], dnS);
    }
  }

  // row denominators: lane holds row mr's partial (its k-slice); sum 4 grps
  dnD += __shfl_xor(dnD, 16, 64); dnD += __shfl_xor(dnD, 32, 64);
  dnS += __shfl_xor(dnS, 16, 64); dnS += __shfl_xor(dnS, 32, 64);

  // partials: pn[((c*256+t)*8+h)*2+g][row][col], pd[((c*256+t)*8+h)*2+g][row]
  float* pnb = pn + ((((size_t)c * 256 + t) * 8 + h) * 2) * 256;
  #pragma unroll
  for (int r = 0; r < 4; ++r) {
    const int row = grp * 4 + r;
    pnb[row * 16 + mr]       = accD[r];
    pnb[256 + row * 16 + mr] = accS[r];
  }
  if (lane < 16) {
    float* pdb = pd + ((((size_t)c * 256 + t) * 8 + h) * 2) * 16;
    pdb[lane]      = dnD;   // row = lane (mr), full sum after reduction
    pdb[16 + lane] = dnS;
  }
}

// ---- K3: reduce partials, normalize, output GEMM. grid 256 x 512 ----
__global__ __launch_bounds__(512) void k_reduce(
    const float* __restrict__ pn, const float* __restrict__ pd,
    const unsigned short* __restrict__ Xb, const unsigned short* __restrict__ WpT,
    const float* __restrict__ bsum, float* __restrict__ out)
{
  __shared__ unsigned short catT[16][520];  // [row][ S(128) | D(128) | X(256) ]
  const int t = blockIdx.x, i0 = t * 16;
  const int tid = threadIdx.x;
  {  // stage X rows -> catT cols 256..511
    const int r = tid >> 5, x0 = (tid & 31) * 8;
    *(bf16x8*)(&catT[r][256 + x0]) = *(const bf16x8*)(Xb + (size_t)(i0 + r) * 256 + x0);
  }
  const int h = tid >> 6, lane = tid & 63;
  const int mr = lane & 15, grp = lane >> 4;

  #pragma unroll
  for (int r = 0; r < 4; ++r) {
    const int row = grp * 4 + r;
    float vD = 0.f, vS = 0.f, dD = 0.f, dS = 0.f;
    #pragma unroll
    for (int c = 0; c < NS; ++c) {
      const size_t nb = ((((size_t)c * 256 + t) * 8 + h) * 2) * 256;
      const size_t db = ((((size_t)c * 256 + t) * 8 + h) * 2) * 16;
      vD += pn[nb + row * 16 + mr];
      vS += pn[nb + 256 + row * 16 + mr];
      dD += pd[db + row];
      dS += pd[db + 16 + row];
    }
    const float oS = vS * __builtin_amdgcn_rcpf(fmaxf(dS, 1e-30f));
    const float oD = vD * __builtin_amdgcn_rcpf(fmaxf(dD, 1e-30f));
    catT[row][h * 16 + mr]       = f2bf_rn(oS);
    catT[row][128 + h * 16 + mr] = f2bf_rn(oD);
  }
  __syncthreads();

  // phase B: out[16][128] = catT[16][512] @ W'[512][128] + bsum
  f32x4 o = {0.f, 0.f, 0.f, 0.f};
  const unsigned short* wp = WpT + (size_t)(h * 16 + mr) * 512;
  #pragma unroll
  for (int ks = 0; ks < 16; ++ks) {
    bf16x8 a = *(const bf16x8*)(&catT[mr][ks * 32 + grp * 8]);
    bf16x8 b = *(const bf16x8*)(wp + ks * 32 + grp * 8);
    o = __builtin_amdgcn_mfma_f32_16x16x32_bf16(a, b, o, 0, 0, 0);
  }
  const float bs = bsum[h * 16 + mr];
  #pragma unroll
  for (int r = 0; r < 4; ++r)
    out[(size_t)(i0 + grp * 4 + r) * 128 + h * 16 + mr] = o[r] + bs;
}

extern "C" void kernel_launch(void* const* d_in, const int* in_sizes, int n_in,
                              void* d_out, int out_size, void* d_ws, size_t ws_size,
                              hipStream_t stream) {
  const float* X    = (const float*)d_in[0];
  const float* Dg   = (const float*)d_in[1];
  const float* Sg   = (const float*)d_in[2];
  const float* Ww   = (const float*)d_in[3];
  const float* Wb   = (const float*)d_in[4];
  const float* wu   = (const float*)d_in[5];
  const float* wv   = (const float*)d_in[6];
  const float* Wcat = (const float*)d_in[7];
  const float* Wcb  = (const float*)d_in[8];
  const float* bias = (const float*)d_in[9];
  const float* proj = (const float*)d_in[10];
  const float* prb  = (const float*)d_in[11];
  float* out = (float*)d_out;

  char* ws = (char*)d_ws;
  unsigned short* Xb   = (unsigned short*)(ws);               // 2 MB
  unsigned short* scT  = (unsigned short*)(ws + 0x200000);    // 1 MB (f16)
  float*          f2   = (float*)(ws + 0x300000);             // 128 KB
  unsigned short* E1p  = (unsigned short*)(ws + 0x320000);    // 64 KB (f16)
  unsigned short* E3p  = (unsigned short*)(ws + 0x330000);    // 64 KB (f16)
  unsigned short* WwT  = (unsigned short*)(ws + 0x340000);    // 64 KB
  unsigned short* WpT  = (unsigned short*)(ws + 0x350000);    // 128 KB
  float*          bsum = (float*)(ws + 0x370000);             // 512 B
  unsigned char*  mDS  = (unsigned char*)(ws + 0x400000);     // 32 MB interleaved
  float*          pn   = (float*)(ws + 0x2400000);            // 16 MB
  float*          pd   = (float*)(ws + 0x3400000);            // 1 MB

  k_prep<<<dim3(512), dim3(256), 0, stream>>>(X, Ww, Wcat, proj, Wcb, bias, prb,
                                              Xb, WwT, WpT, bsum);
  k_cvt<<<dim3(8192), dim3(256), 0, stream>>>(Dg, Sg, mDS);
  k_score<<<dim3(256), dim3(512), 0, stream>>>(Xb, WwT, Wb, wu, wv, scT, f2, E1p, E3p);
  k_attn<<<dim3(NS * 256), dim3(512), 0, stream>>>(mDS, scT, E1p, E3p, f2, pn, pd);
  k_reduce<<<dim3(256), dim3(512), 0, stream>>>(pn, pd, Xb, WpT, bsum, out);
}